// Round 1
// baseline (289.153 us; speedup 1.0000x reference)
//
#include <hip/hip_runtime.h>
#include <hip/hip_bf16.h>

// Problem: B=16, C=512, H=W=64 -> HW=4096, fp32.
// attn[b,c,d] = sum_n q[b,c,n]*kv[b,d,n]; P = softmax_d(attn);
// info[b,c,n] = sum_d P[b,c,d]*kv[b,d,n]; out = gamma*info + img.

constexpr int NB = 16;
constexpr int NC = 512;
constexpr int NHW = 4096;

typedef float f32x4 __attribute__((ext_vector_type(4)));
typedef __bf16 bf16x4 __attribute__((ext_vector_type(4)));
typedef __bf16 bf16x8 __attribute__((ext_vector_type(8)));

// ---------------------------------------------------------------------------
// Batched GEMM  D[m][n'] = sum_k A[m][k] * B[n'][k]   (A: [M][K], B: [N][K],
// both row-major K-contiguous, i.e. C = A * B^T).
// Tile 128x128, BK=64, 512 threads = 8 waves (2x4), wave tile 64x32,
// 16x16x32 bf16 MFMA. LDS XOR-swizzled (T2-lite) so ds_read_b128 of fragment
// rows is conflict-free.
// EPI==0: store D as f32 to Dp[b][m][n']            (attn logits)
// EPI==1: out[b][n'][m] = gamma*D[m][n'] + img[...] (m = spatial, n' = chan)
// ---------------------------------------------------------------------------
template <int STAGEF32, int EPI, int MDIM, int NDIM, int KDIM>
__global__ __launch_bounds__(512) void gemm_bt(
    const void* __restrict__ Ap, const void* __restrict__ Bp,
    float* __restrict__ Dp, const float* __restrict__ img,
    const float* __restrict__ gammap, float* __restrict__ outp) {
  __shared__ __bf16 sA[128 * 64];
  __shared__ __bf16 sB[128 * 64];

  const int t = threadIdx.x;
  const int lane = t & 63;
  const int wave = t >> 6;
  const int wr = wave >> 2;  // 0..1 -> M offset wr*64
  const int wc = wave & 3;   // 0..3 -> N offset wc*32

  const long aBatch = (long)blockIdx.z * MDIM * KDIM;
  const long bBatch = (long)blockIdx.z * NDIM * KDIM;
  const int aRow0 = blockIdx.x * 128;
  const int bRow0 = blockIdx.y * 128;

  f32x4 acc[4][2] = {};

  for (int k0 = 0; k0 < KDIM; k0 += 64) {
    // ---- stage A,B tiles (128x64) into swizzled LDS as bf16 ----
    if constexpr (STAGEF32) {
      const float* A = (const float*)Ap + aBatch;
      const float* Bm = (const float*)Bp + bBatch;
      const int c4 = (t & 15) * 4;  // k offset
      const int rb = t >> 4;        // 0..31
#pragma unroll
      for (int i = 0; i < 4; ++i) {
        const int r = rb + 32 * i;
        f32x4 va = *(const f32x4*)(A + (long)(aRow0 + r) * KDIM + k0 + c4);
        f32x4 vb = *(const f32x4*)(Bm + (long)(bRow0 + r) * KDIM + k0 + c4);
        const int idx = r * 64 + (c4 ^ ((r & 7) << 3));
        bf16x4 ha = {(__bf16)va.x, (__bf16)va.y, (__bf16)va.z, (__bf16)va.w};
        bf16x4 hb = {(__bf16)vb.x, (__bf16)vb.y, (__bf16)vb.z, (__bf16)vb.w};
        *(bf16x4*)&sA[idx] = ha;
        *(bf16x4*)&sB[idx] = hb;
      }
    } else {
      const __bf16* A = (const __bf16*)Ap + aBatch;
      const __bf16* Bm = (const __bf16*)Bp + bBatch;
      const int c8 = (t & 7) * 8;  // k offset
      const int rb = t >> 3;       // 0..63
#pragma unroll
      for (int i = 0; i < 2; ++i) {
        const int r = rb + 64 * i;
        bf16x8 va = *(const bf16x8*)(A + (long)(aRow0 + r) * KDIM + k0 + c8);
        bf16x8 vb = *(const bf16x8*)(Bm + (long)(bRow0 + r) * KDIM + k0 + c8);
        const int idx = r * 64 + (c8 ^ ((r & 7) << 3));
        *(bf16x8*)&sA[idx] = va;
        *(bf16x8*)&sB[idx] = vb;
      }
    }
    __syncthreads();

    // ---- MFMA over the 64-deep K slab ----
#pragma unroll
    for (int kk = 0; kk < 2; ++kk) {
      const int kb = kk * 32 + ((lane >> 4) << 3);
      bf16x8 af[4], bfr[2];
#pragma unroll
      for (int m = 0; m < 4; ++m) {
        const int r = wr * 64 + m * 16 + (lane & 15);
        af[m] = *(const bf16x8*)&sA[r * 64 + (kb ^ ((r & 7) << 3))];
      }
#pragma unroll
      for (int n = 0; n < 2; ++n) {
        const int r = wc * 32 + n * 16 + (lane & 15);
        bfr[n] = *(const bf16x8*)&sB[r * 64 + (kb ^ ((r & 7) << 3))];
      }
#pragma unroll
      for (int m = 0; m < 4; ++m)
#pragma unroll
        for (int n = 0; n < 2; ++n)
          acc[m][n] = __builtin_amdgcn_mfma_f32_16x16x32_bf16(
              af[m], bfr[n], acc[m][n], 0, 0, 0);
    }
    __syncthreads();
  }

  // ---- epilogue ----
  // C/D layout (m89): col = lane&15, row = (lane>>4)*4 + reg
  if constexpr (EPI == 0) {
    float* D = Dp + (long)blockIdx.z * MDIM * NDIM;
    const int m0 = aRow0 + wr * 64;
    const int n0 = bRow0 + wc * 32;
#pragma unroll
    for (int m = 0; m < 4; ++m)
#pragma unroll
      for (int n = 0; n < 2; ++n) {
        const int row0 = m0 + m * 16 + ((lane >> 4) << 2);
        const int col = n0 + n * 16 + (lane & 15);
#pragma unroll
        for (int r = 0; r < 4; ++r)
          D[(long)(row0 + r) * NDIM + col] = acc[m][n][r];
      }
  } else {
    const float g = gammap[0];
    const long obase = (long)blockIdx.z * NC * NHW;
    const int sp0 = aRow0 + wr * 64;   // spatial (m)
    const int ch0 = bRow0 + wc * 32;   // channel (n')
#pragma unroll
    for (int m = 0; m < 4; ++m)
#pragma unroll
      for (int n = 0; n < 2; ++n) {
        const int sp = sp0 + m * 16 + ((lane >> 4) << 2);
        const int ch = ch0 + n * 16 + (lane & 15);
        const long idx = obase + (long)ch * NHW + sp;
        f32x4 iv = *(const f32x4*)(img + idx);
        f32x4 ov;
#pragma unroll
        for (int r = 0; r < 4; ++r) ov[r] = g * acc[m][n][r] + iv[r];
        *(f32x4*)(outp + idx) = ov;
      }
  }
}

// ---------------------------------------------------------------------------
// Transpose + cast: kv[b][d][n] (f32) -> kvT[b][n][d] (bf16). 64x64 tiles.
// ---------------------------------------------------------------------------
__global__ __launch_bounds__(256) void transpose_cast(
    const float* __restrict__ kv, __bf16* __restrict__ kvT) {
  __shared__ __bf16 tile[64 * 68];  // [d][n], pitch 68 (136B, 16B-misalign-free for 8B writes, bank-spread)
  const int t = threadIdx.x;
  const int n0 = blockIdx.x * 64;
  const int d0 = blockIdx.y * 64;
  const long ibase = (long)blockIdx.z * NC * NHW;

  const int nc4 = (t & 15) * 4;
  const int dr0 = t >> 4;  // 0..15
#pragma unroll
  for (int i = 0; i < 4; ++i) {
    const int dr = dr0 + 16 * i;
    f32x4 v = *(const f32x4*)(kv + ibase + (long)(d0 + dr) * NHW + n0 + nc4);
    bf16x4 h = {(__bf16)v.x, (__bf16)v.y, (__bf16)v.z, (__bf16)v.w};
    *(bf16x4*)&tile[dr * 68 + nc4] = h;
  }
  __syncthreads();

  const long obase = (long)blockIdx.z * NHW * NC;
  const int nr = t >> 2;   // 0..63
  const int dc0 = t & 3;
#pragma unroll
  for (int i = 0; i < 2; ++i) {
    const int dc = dc0 + 4 * i;  // 0..7, 8 bf16 each
    bf16x8 pk;
#pragma unroll
    for (int j = 0; j < 8; ++j) pk[j] = tile[(dc * 8 + j) * 68 + nr];
    *(bf16x8*)(kvT + obase + (long)(n0 + nr) * NC + d0 + dc * 8) = pk;
  }
}

// ---------------------------------------------------------------------------
// Row softmax: attn[row][0..511] f32 -> P bf16. One wave per row.
// ---------------------------------------------------------------------------
__global__ __launch_bounds__(256) void softmax_rows(
    const float* __restrict__ attn, __bf16* __restrict__ P) {
  const int row = blockIdx.x * 4 + (threadIdx.x >> 6);
  const int lane = threadIdx.x & 63;
  const float* src = attn + (long)row * NC;

  f32x4 v0 = *(const f32x4*)(src + lane * 4);
  f32x4 v1 = *(const f32x4*)(src + 256 + lane * 4);
  float x[8];
#pragma unroll
  for (int r = 0; r < 4; ++r) { x[r] = v0[r]; x[4 + r] = v1[r]; }

  float mx = x[0];
#pragma unroll
  for (int r = 1; r < 8; ++r) mx = fmaxf(mx, x[r]);
#pragma unroll
  for (int off = 32; off >= 1; off >>= 1) mx = fmaxf(mx, __shfl_xor(mx, off));

  float e[8], s = 0.f;
#pragma unroll
  for (int r = 0; r < 8; ++r) { e[r] = expf(x[r] - mx); s += e[r]; }
#pragma unroll
  for (int off = 32; off >= 1; off >>= 1) s += __shfl_xor(s, off);
  const float inv = 1.0f / s;

  __bf16* dst = P + (long)row * NC;
  bf16x4 h0, h1;
#pragma unroll
  for (int r = 0; r < 4; ++r) {
    h0[r] = (__bf16)(e[r] * inv);
    h1[r] = (__bf16)(e[4 + r] * inv);
  }
  *(bf16x4*)(dst + lane * 4) = h0;
  *(bf16x4*)(dst + 256 + lane * 4) = h1;
}

// ---------------------------------------------------------------------------
extern "C" void kernel_launch(void* const* d_in, const int* in_sizes, int n_in,
                              void* d_out, int out_size, void* d_ws,
                              size_t ws_size, hipStream_t stream) {
  const float* img = (const float*)d_in[0];   // q source
  const float* txt = (const float*)d_in[1];   // kv source
  const float* gamma = (const float*)d_in[2];
  float* out = (float*)d_out;

  char* ws = (char*)d_ws;
  float* attn = (float*)ws;                                    // 16 MB f32
  __bf16* P = (__bf16*)(ws + (size_t)16 * 1024 * 1024);        //  8 MB bf16
  __bf16* kvT = (__bf16*)(ws + (size_t)24 * 1024 * 1024);      // 64 MB bf16
  // total ws use: 88 MB

  // 1) attn = q * kv^T  (per batch 512x512, K=4096)
  gemm_bt<1, 0, NC, NC, NHW><<<dim3(NC / 128, NC / 128, NB), 512, 0, stream>>>(
      img, txt, attn, nullptr, nullptr, nullptr);

  // 2) kvT[b][n][d] = bf16(kv[b][d][n])
  transpose_cast<<<dim3(NHW / 64, NC / 64, NB), 256, 0, stream>>>(txt, kvT);

  // 3) P = softmax_rows(attn), bf16
  softmax_rows<<<dim3(NB * NC / 4), 256, 0, stream>>>(attn, P);

  // 4) D[n][c] = sum_d kvT[n][d]*P[c][d] = info[c][n];
  //    out[b][c][n] = gamma*D + img  (per batch 4096x512, K=512)
  gemm_bt<0, 1, NHW, NC, NC><<<dim3(NHW / 128, NC / 128, NB), 512, 0, stream>>>(
      kvT, P, nullptr, img, gamma, out);
}

// Round 2
// 257.994 us; speedup vs baseline: 1.1208x; 1.1208x over previous
//
#include <hip/hip_runtime.h>
#include <hip/hip_bf16.h>

// Problem: B=16, C=512, H=W=64 -> HW=4096, fp32.
// attn[b,c,d] = sum_n q[b,c,n]*kv[b,d,n]; P = softmax_d(attn);
// info[b,c,n] = sum_d P[b,c,d]*kv[b,d,n]; out = gamma*info + img.

constexpr int NB = 16;
constexpr int NC = 512;
constexpr int NHW = 4096;
constexpr int SPLITK = 4;  // split-K factor for the attn GEMM

typedef float f32x4 __attribute__((ext_vector_type(4)));
typedef __bf16 bf16x4 __attribute__((ext_vector_type(4)));
typedef __bf16 bf16x8 __attribute__((ext_vector_type(8)));

// ---------------------------------------------------------------------------
// Batched GEMM  D[m][n'] = sum_k A[m][k] * B[n'][k]   (A: [M][K], B: [N][K],
// both row-major K-contiguous, i.e. C = A * B^T).
// Tile 128x128, BK=64, 512 threads = 8 waves (2x4), wave tile 64x32,
// 16x16x32 bf16 MFMA. LDS XOR-swizzled: measured 0 bank conflicts (R1).
// blockIdx.z = batch*SPLITS + split; each split covers KDIM/SPLITS.
// EPI==0: store partial D as f32 to Dp[split][b][m][n']   (attn logits)
// EPI==1: out[b][n'][m] = gamma*D[m][n'] + img[...] (m = spatial, n' = chan)
// ---------------------------------------------------------------------------
template <int STAGEF32, int EPI, int MDIM, int NDIM, int KDIM, int SPLITS>
__global__ __launch_bounds__(512) void gemm_bt(
    const void* __restrict__ Ap, const void* __restrict__ Bp,
    float* __restrict__ Dp, const float* __restrict__ img,
    const float* __restrict__ gammap, float* __restrict__ outp) {
  __shared__ __bf16 sA[128 * 64];
  __shared__ __bf16 sB[128 * 64];

  const int t = threadIdx.x;
  const int lane = t & 63;
  const int wave = t >> 6;
  const int wr = wave >> 2;  // 0..1 -> M offset wr*64
  const int wc = wave & 3;   // 0..3 -> N offset wc*32

  const int batch = blockIdx.z / SPLITS;
  const int split = blockIdx.z % SPLITS;

  const long aBatch = (long)batch * MDIM * KDIM;
  const long bBatch = (long)batch * NDIM * KDIM;
  const int aRow0 = blockIdx.x * 128;
  const int bRow0 = blockIdx.y * 128;

  constexpr int KSUB = KDIM / SPLITS;
  const int kBeg = split * KSUB;
  const int kEnd = kBeg + KSUB;

  f32x4 acc[4][2] = {};

  for (int k0 = kBeg; k0 < kEnd; k0 += 64) {
    // ---- stage A,B tiles (128x64) into swizzled LDS as bf16 ----
    if constexpr (STAGEF32) {
      const float* A = (const float*)Ap + aBatch;
      const float* Bm = (const float*)Bp + bBatch;
      const int c4 = (t & 15) * 4;  // k offset
      const int rb = t >> 4;        // 0..31
#pragma unroll
      for (int i = 0; i < 4; ++i) {
        const int r = rb + 32 * i;
        f32x4 va = *(const f32x4*)(A + (long)(aRow0 + r) * KDIM + k0 + c4);
        f32x4 vb = *(const f32x4*)(Bm + (long)(bRow0 + r) * KDIM + k0 + c4);
        const int idx = r * 64 + (c4 ^ ((r & 7) << 3));
        bf16x4 ha = {(__bf16)va.x, (__bf16)va.y, (__bf16)va.z, (__bf16)va.w};
        bf16x4 hb = {(__bf16)vb.x, (__bf16)vb.y, (__bf16)vb.z, (__bf16)vb.w};
        *(bf16x4*)&sA[idx] = ha;
        *(bf16x4*)&sB[idx] = hb;
      }
    } else {
      const __bf16* A = (const __bf16*)Ap + aBatch;
      const __bf16* Bm = (const __bf16*)Bp + bBatch;
      const int c8 = (t & 7) * 8;  // k offset
      const int rb = t >> 3;       // 0..63
#pragma unroll
      for (int i = 0; i < 2; ++i) {
        const int r = rb + 64 * i;
        bf16x8 va = *(const bf16x8*)(A + (long)(aRow0 + r) * KDIM + k0 + c8);
        bf16x8 vb = *(const bf16x8*)(Bm + (long)(bRow0 + r) * KDIM + k0 + c8);
        const int idx = r * 64 + (c8 ^ ((r & 7) << 3));
        *(bf16x8*)&sA[idx] = va;
        *(bf16x8*)&sB[idx] = vb;
      }
    }
    __syncthreads();

    // ---- MFMA over the 64-deep K slab ----
#pragma unroll
    for (int kk = 0; kk < 2; ++kk) {
      const int kb = kk * 32 + ((lane >> 4) << 3);
      bf16x8 af[4], bfr[2];
#pragma unroll
      for (int m = 0; m < 4; ++m) {
        const int r = wr * 64 + m * 16 + (lane & 15);
        af[m] = *(const bf16x8*)&sA[r * 64 + (kb ^ ((r & 7) << 3))];
      }
#pragma unroll
      for (int n = 0; n < 2; ++n) {
        const int r = wc * 32 + n * 16 + (lane & 15);
        bfr[n] = *(const bf16x8*)&sB[r * 64 + (kb ^ ((r & 7) << 3))];
      }
#pragma unroll
      for (int m = 0; m < 4; ++m)
#pragma unroll
        for (int n = 0; n < 2; ++n)
          acc[m][n] = __builtin_amdgcn_mfma_f32_16x16x32_bf16(
              af[m], bfr[n], acc[m][n], 0, 0, 0);
    }
    __syncthreads();
  }

  // ---- epilogue ----
  // C/D layout (m89): col = lane&15, row = (lane>>4)*4 + reg
  if constexpr (EPI == 0) {
    float* D = Dp + ((long)split * NB + batch) * MDIM * NDIM;
    const int m0 = aRow0 + wr * 64;
    const int n0 = bRow0 + wc * 32;
#pragma unroll
    for (int m = 0; m < 4; ++m)
#pragma unroll
      for (int n = 0; n < 2; ++n) {
        const int row0 = m0 + m * 16 + ((lane >> 4) << 2);
        const int col = n0 + n * 16 + (lane & 15);
#pragma unroll
        for (int r = 0; r < 4; ++r)
          D[(long)(row0 + r) * NDIM + col] = acc[m][n][r];
      }
  } else {
    const float g = gammap[0];
    const long obase = (long)batch * NC * NHW;
    const int sp0 = aRow0 + wr * 64;   // spatial (m)
    const int ch0 = bRow0 + wc * 32;   // channel (n')
#pragma unroll
    for (int m = 0; m < 4; ++m)
#pragma unroll
      for (int n = 0; n < 2; ++n) {
        const int sp = sp0 + m * 16 + ((lane >> 4) << 2);
        const int ch = ch0 + n * 16 + (lane & 15);
        const long idx = obase + (long)ch * NHW + sp;
        f32x4 iv = *(const f32x4*)(img + idx);
        f32x4 ov;
#pragma unroll
        for (int r = 0; r < 4; ++r) ov[r] = g * acc[m][n][r] + iv[r];
        *(f32x4*)(outp + idx) = ov;
      }
  }
}

// ---------------------------------------------------------------------------
// Transpose + cast: kv[b][d][n] (f32) -> kvT[b][n][d] (bf16). 64x64 tiles.
// ---------------------------------------------------------------------------
__global__ __launch_bounds__(256) void transpose_cast(
    const float* __restrict__ kv, __bf16* __restrict__ kvT) {
  __shared__ __bf16 tile[64 * 68];  // [d][n], pitch 68
  const int t = threadIdx.x;
  const int n0 = blockIdx.x * 64;
  const int d0 = blockIdx.y * 64;
  const long ibase = (long)blockIdx.z * NC * NHW;

  const int nc4 = (t & 15) * 4;
  const int dr0 = t >> 4;  // 0..15
#pragma unroll
  for (int i = 0; i < 4; ++i) {
    const int dr = dr0 + 16 * i;
    f32x4 v = *(const f32x4*)(kv + ibase + (long)(d0 + dr) * NHW + n0 + nc4);
    bf16x4 h = {(__bf16)v.x, (__bf16)v.y, (__bf16)v.z, (__bf16)v.w};
    *(bf16x4*)&tile[dr * 68 + nc4] = h;
  }
  __syncthreads();

  const long obase = (long)blockIdx.z * NHW * NC;
  const int nr = t >> 2;   // 0..63
  const int dc0 = t & 3;
#pragma unroll
  for (int i = 0; i < 2; ++i) {
    const int dc = dc0 + 4 * i;  // 0..7, 8 bf16 each
    bf16x8 pk;
#pragma unroll
    for (int j = 0; j < 8; ++j) pk[j] = tile[(dc * 8 + j) * 68 + nr];
    *(bf16x8*)(kvT + obase + (long)(n0 + nr) * NC + d0 + dc * 8) = pk;
  }
}

// ---------------------------------------------------------------------------
// Row softmax with split-K reduction: attn partials [SPLITK][row][0..511] f32
// -> P bf16. One wave per row.
// ---------------------------------------------------------------------------
__global__ __launch_bounds__(256) void softmax_rows(
    const float* __restrict__ attn, __bf16* __restrict__ P) {
  const int row = blockIdx.x * 4 + (threadIdx.x >> 6);
  const int lane = threadIdx.x & 63;
  const long PS = (long)NB * NC * NC;  // split stride (elements)
  const float* src = attn + (long)row * NC;

  float x[8] = {0.f, 0.f, 0.f, 0.f, 0.f, 0.f, 0.f, 0.f};
#pragma unroll
  for (int s = 0; s < SPLITK; ++s) {
    f32x4 v0 = *(const f32x4*)(src + s * PS + lane * 4);
    f32x4 v1 = *(const f32x4*)(src + s * PS + 256 + lane * 4);
#pragma unroll
    for (int r = 0; r < 4; ++r) { x[r] += v0[r]; x[4 + r] += v1[r]; }
  }

  float mx = x[0];
#pragma unroll
  for (int r = 1; r < 8; ++r) mx = fmaxf(mx, x[r]);
#pragma unroll
  for (int off = 32; off >= 1; off >>= 1) mx = fmaxf(mx, __shfl_xor(mx, off));

  float e[8], s = 0.f;
#pragma unroll
  for (int r = 0; r < 8; ++r) { e[r] = expf(x[r] - mx); s += e[r]; }
#pragma unroll
  for (int off = 32; off >= 1; off >>= 1) s += __shfl_xor(s, off);
  const float inv = 1.0f / s;

  __bf16* dst = P + (long)row * NC;
  bf16x4 h0, h1;
#pragma unroll
  for (int r = 0; r < 4; ++r) {
    h0[r] = (__bf16)(e[r] * inv);
    h1[r] = (__bf16)(e[4 + r] * inv);
  }
  *(bf16x4*)(dst + lane * 4) = h0;
  *(bf16x4*)(dst + 256 + lane * 4) = h1;
}

// ---------------------------------------------------------------------------
extern "C" void kernel_launch(void* const* d_in, const int* in_sizes, int n_in,
                              void* d_out, int out_size, void* d_ws,
                              size_t ws_size, hipStream_t stream) {
  const float* img = (const float*)d_in[0];   // q source
  const float* txt = (const float*)d_in[1];   // kv source
  const float* gamma = (const float*)d_in[2];
  float* out = (float*)d_out;

  char* ws = (char*)d_ws;
  // [0, 64MB): attn split-K partials (4 x 16MB f32); AFTER softmax this
  //            region is dead and kvT (64MB bf16) aliases it.
  // [64MB, 72MB): P (bf16)
  float* attnP = (float*)ws;
  __bf16* kvT = (__bf16*)ws;  // alias — written only after softmax completes
  __bf16* P = (__bf16*)(ws + (size_t)64 * 1024 * 1024);

  // 1) attn partials = q * kv^T  (per batch 512x512, K=4096 split 4 ways)
  //    grid 4x4x(16*4) = 1024 blocks -> 4 blocks/CU, 100% occupancy target.
  gemm_bt<1, 0, NC, NC, NHW, SPLITK>
      <<<dim3(NC / 128, NC / 128, NB * SPLITK), 512, 0, stream>>>(
          img, txt, attnP, nullptr, nullptr, nullptr);

  // 2) P = softmax_rows(sum of partials), bf16
  softmax_rows<<<dim3(NB * NC / 4), 256, 0, stream>>>(attnP, P);

  // 3) kvT[b][n][d] = bf16(kv[b][d][n])   (aliases the dead partials region)
  transpose_cast<<<dim3(NHW / 64, NC / 64, NB), 256, 0, stream>>>(txt, kvT);

  // 4) D[n][c] = sum_d kvT[n][d]*P[c][d] = info[c][n];
  //    out[b][c][n] = gamma*D + img  (per batch 4096x512, K=512)
  gemm_bt<0, 1, NHW, NC, NC, 1>
      <<<dim3(NHW / 128, NC / 128, NB), 512, 0, stream>>>(
          kvT, P, nullptr, img, gamma, out);
}

// Round 3
// 230.317 us; speedup vs baseline: 1.2555x; 1.1202x over previous
//
#include <hip/hip_runtime.h>
#include <hip/hip_bf16.h>

// Problem: B=16, C=512, H=W=64 -> HW=4096, fp32.
// attn[b,c,d] = sum_n q[b,c,n]*kv[b,d,n]; P = softmax_d(attn);
// info[b,c,n] = sum_d P[b,c,d]*kv[b,d,n]; out = gamma*info + img.

constexpr int NB = 16;
constexpr int NC = 512;
constexpr int NHW = 4096;
constexpr int SPLITK = 4;  // split-K factor for the attn GEMM

typedef float f32x4 __attribute__((ext_vector_type(4)));
typedef __bf16 bf16x4 __attribute__((ext_vector_type(4)));
typedef __bf16 bf16x8 __attribute__((ext_vector_type(8)));

// ---------------------------------------------------------------------------
// Batched GEMM  D[m][n'] = sum_k A[m][k] * B[n'][k]   (A: [M][K], B: [N][K],
// both row-major K-contiguous, i.e. C = A * B^T).
// Tile 128x128, BK=64, 512 threads = 8 waves (2x4), wave tile 64x32,
// 16x16x32 bf16 MFMA. LDS XOR-swizzled: measured 0 bank conflicts (R1/R2).
// R3: T14 async staging — next k-tile's global loads issued into registers
// BEFORE computing the current tile; reg->LDS write after the post-compute
// barrier. T1 XCD swizzle on the flat block id (same-batch tiles co-XCD).
// blockIdx.z = batch*SPLITS + split; each split covers KDIM/SPLITS.
// EPI==0: store partial D as f32 to Dp[split][b][m][n']   (attn logits)
// EPI==1: out[b][n'][m] = gamma*D[m][n'] + img[...] (m = spatial, n' = chan)
// ---------------------------------------------------------------------------
template <int STAGEF32, int EPI, int MDIM, int NDIM, int KDIM, int SPLITS>
__global__ __launch_bounds__(512) void gemm_bt(
    const void* __restrict__ Ap, const void* __restrict__ Bp,
    float* __restrict__ Dp, const float* __restrict__ img,
    const float* __restrict__ gammap, float* __restrict__ outp) {
  __shared__ __bf16 sA[128 * 64];
  __shared__ __bf16 sB[128 * 64];

  const int t = threadIdx.x;
  const int lane = t & 63;
  const int wave = t >> 6;
  const int wr = wave >> 2;  // 0..1 -> M offset wr*64
  const int wc = wave & 3;   // 0..3 -> N offset wc*32

  // ---- T1: XCD-aware remap of the flat workgroup id (nwg % 8 == 0) ----
  constexpr int GX = MDIM / 128;
  constexpr int GY = NDIM / 128;
  constexpr int NWG = GX * GY * NB * SPLITS;
  constexpr int QX = NWG / 8;
  int flat = blockIdx.x + GX * (blockIdx.y + GY * blockIdx.z);
  flat = (flat & 7) * QX + (flat >> 3);
  const int bx = flat % GX;
  const int by = (flat / GX) % GY;
  const int bz = flat / (GX * GY);

  const int batch = bz / SPLITS;
  const int split = bz % SPLITS;

  const long aBatch = (long)batch * MDIM * KDIM;
  const long bBatch = (long)batch * NDIM * KDIM;
  const int aRow0 = bx * 128;
  const int bRow0 = by * 128;

  constexpr int KSUB = KDIM / SPLITS;
  const int kBeg = split * KSUB;
  const int kEnd = kBeg + KSUB;

  f32x4 acc[4][2] = {};

  // staged-tile registers (one k-tile in flight)
  f32x4 ra[4], rb4[4];    // STAGEF32 path
  bf16x8 ha8[2], hb8[2];  // bf16 path

  auto stage_load = [&](int k0) {
    if constexpr (STAGEF32) {
      const float* A = (const float*)Ap + aBatch;
      const float* Bm = (const float*)Bp + bBatch;
      const int c4 = (t & 15) * 4;
      const int rb = t >> 4;
#pragma unroll
      for (int i = 0; i < 4; ++i) {
        const int r = rb + 32 * i;
        ra[i] = *(const f32x4*)(A + (long)(aRow0 + r) * KDIM + k0 + c4);
        rb4[i] = *(const f32x4*)(Bm + (long)(bRow0 + r) * KDIM + k0 + c4);
      }
    } else {
      const __bf16* A = (const __bf16*)Ap + aBatch;
      const __bf16* Bm = (const __bf16*)Bp + bBatch;
      const int c8 = (t & 7) * 8;
      const int rb = t >> 3;
#pragma unroll
      for (int i = 0; i < 2; ++i) {
        const int r = rb + 64 * i;
        ha8[i] = *(const bf16x8*)(A + (long)(aRow0 + r) * KDIM + k0 + c8);
        hb8[i] = *(const bf16x8*)(Bm + (long)(bRow0 + r) * KDIM + k0 + c8);
      }
    }
  };

  auto stage_write = [&]() {
    if constexpr (STAGEF32) {
      const int c4 = (t & 15) * 4;
      const int rb = t >> 4;
#pragma unroll
      for (int i = 0; i < 4; ++i) {
        const int r = rb + 32 * i;
        const int idx = r * 64 + (c4 ^ ((r & 7) << 3));
        bf16x4 ha = {(__bf16)ra[i].x, (__bf16)ra[i].y, (__bf16)ra[i].z,
                     (__bf16)ra[i].w};
        bf16x4 hb = {(__bf16)rb4[i].x, (__bf16)rb4[i].y, (__bf16)rb4[i].z,
                     (__bf16)rb4[i].w};
        *(bf16x4*)&sA[idx] = ha;
        *(bf16x4*)&sB[idx] = hb;
      }
    } else {
      const int c8 = (t & 7) * 8;
      const int rb = t >> 3;
#pragma unroll
      for (int i = 0; i < 2; ++i) {
        const int r = rb + 64 * i;
        const int idx = r * 64 + (c8 ^ ((r & 7) << 3));
        *(bf16x8*)&sA[idx] = ha8[i];
        *(bf16x8*)&sB[idx] = hb8[i];
      }
    }
  };

  auto compute_tile = [&]() {
#pragma unroll
    for (int kk = 0; kk < 2; ++kk) {
      const int kb = kk * 32 + ((lane >> 4) << 3);
      bf16x8 af[4], bfr[2];
#pragma unroll
      for (int m = 0; m < 4; ++m) {
        const int r = wr * 64 + m * 16 + (lane & 15);
        af[m] = *(const bf16x8*)&sA[r * 64 + (kb ^ ((r & 7) << 3))];
      }
#pragma unroll
      for (int n = 0; n < 2; ++n) {
        const int r = wc * 32 + n * 16 + (lane & 15);
        bfr[n] = *(const bf16x8*)&sB[r * 64 + (kb ^ ((r & 7) << 3))];
      }
#pragma unroll
      for (int m = 0; m < 4; ++m)
#pragma unroll
        for (int n = 0; n < 2; ++n)
          acc[m][n] = __builtin_amdgcn_mfma_f32_16x16x32_bf16(
              af[m], bfr[n], acc[m][n], 0, 0, 0);
    }
  };

  // prologue: stage first tile
  stage_load(kBeg);
  stage_write();
  __syncthreads();

#pragma unroll 1
  for (int k0 = kBeg; k0 < kEnd; k0 += 64) {
    const bool more = (k0 + 64) < kEnd;
    if (more) stage_load(k0 + 64);  // issue early — latency hides under MFMA
    compute_tile();
    __syncthreads();  // all waves done reading LDS
    if (more) {
      stage_write();  // vmcnt drain happens here, overlapped w/ prior compute
      __syncthreads();
    }
  }

  // ---- epilogue ----
  // C/D layout (m89): col = lane&15, row = (lane>>4)*4 + reg
  if constexpr (EPI == 0) {
    float* D = Dp + ((long)split * NB + batch) * MDIM * NDIM;
    const int m0 = aRow0 + wr * 64;
    const int n0 = bRow0 + wc * 32;
#pragma unroll
    for (int m = 0; m < 4; ++m)
#pragma unroll
      for (int n = 0; n < 2; ++n) {
        const int row0 = m0 + m * 16 + ((lane >> 4) << 2);
        const int col = n0 + n * 16 + (lane & 15);
#pragma unroll
        for (int r = 0; r < 4; ++r)
          D[(long)(row0 + r) * NDIM + col] = acc[m][n][r];
      }
  } else {
    const float g = gammap[0];
    const long obase = (long)batch * NC * NHW;
    const int sp0 = aRow0 + wr * 64;  // spatial (m)
    const int ch0 = bRow0 + wc * 32;  // channel (n')
#pragma unroll
    for (int m = 0; m < 4; ++m)
#pragma unroll
      for (int n = 0; n < 2; ++n) {
        const int sp = sp0 + m * 16 + ((lane >> 4) << 2);
        const int ch = ch0 + n * 16 + (lane & 15);
        const long idx = obase + (long)ch * NHW + sp;
        f32x4 iv = *(const f32x4*)(img + idx);
        f32x4 ov;
#pragma unroll
        for (int r = 0; r < 4; ++r) ov[r] = g * acc[m][n][r] + iv[r];
        *(f32x4*)(outp + idx) = ov;
      }
  }
}

// ---------------------------------------------------------------------------
// Transpose + cast: kv[b][d][n] (f32) -> kvT[b][n][d] (bf16). 64x64 tiles.
// ---------------------------------------------------------------------------
__global__ __launch_bounds__(256) void transpose_cast(
    const float* __restrict__ kv, __bf16* __restrict__ kvT) {
  __shared__ __bf16 tile[64 * 68];  // [d][n], pitch 68
  const int t = threadIdx.x;
  const int n0 = blockIdx.x * 64;
  const int d0 = blockIdx.y * 64;
  const long ibase = (long)blockIdx.z * NC * NHW;

  const int nc4 = (t & 15) * 4;
  const int dr0 = t >> 4;  // 0..15
#pragma unroll
  for (int i = 0; i < 4; ++i) {
    const int dr = dr0 + 16 * i;
    f32x4 v = *(const f32x4*)(kv + ibase + (long)(d0 + dr) * NHW + n0 + nc4);
    bf16x4 h = {(__bf16)v.x, (__bf16)v.y, (__bf16)v.z, (__bf16)v.w};
    *(bf16x4*)&tile[dr * 68 + nc4] = h;
  }
  __syncthreads();

  const long obase = (long)blockIdx.z * NHW * NC;
  const int nr = t >> 2;  // 0..63
  const int dc0 = t & 3;
#pragma unroll
  for (int i = 0; i < 2; ++i) {
    const int dc = dc0 + 4 * i;  // 0..7, 8 bf16 each
    bf16x8 pk;
#pragma unroll
    for (int j = 0; j < 8; ++j) pk[j] = tile[(dc * 8 + j) * 68 + nr];
    *(bf16x8*)(kvT + obase + (long)(n0 + nr) * NC + d0 + dc * 8) = pk;
  }
}

// ---------------------------------------------------------------------------
// Row softmax with split-K reduction: attn partials [SPLITK][row][0..511] f32
// -> P bf16. One wave per row.
// ---------------------------------------------------------------------------
__global__ __launch_bounds__(256) void softmax_rows(
    const float* __restrict__ attn, __bf16* __restrict__ P) {
  const int row = blockIdx.x * 4 + (threadIdx.x >> 6);
  const int lane = threadIdx.x & 63;
  const long PS = (long)NB * NC * NC;  // split stride (elements)
  const float* src = attn + (long)row * NC;

  float x[8] = {0.f, 0.f, 0.f, 0.f, 0.f, 0.f, 0.f, 0.f};
#pragma unroll
  for (int s = 0; s < SPLITK; ++s) {
    f32x4 v0 = *(const f32x4*)(src + s * PS + lane * 4);
    f32x4 v1 = *(const f32x4*)(src + s * PS + 256 + lane * 4);
#pragma unroll
    for (int r = 0; r < 4; ++r) { x[r] += v0[r]; x[4 + r] += v1[r]; }
  }

  float mx = x[0];
#pragma unroll
  for (int r = 1; r < 8; ++r) mx = fmaxf(mx, x[r]);
#pragma unroll
  for (int off = 32; off >= 1; off >>= 1) mx = fmaxf(mx, __shfl_xor(mx, off));

  float e[8], s = 0.f;
#pragma unroll
  for (int r = 0; r < 8; ++r) { e[r] = expf(x[r] - mx); s += e[r]; }
#pragma unroll
  for (int off = 32; off >= 1; off >>= 1) s += __shfl_xor(s, off);
  const float inv = 1.0f / s;

  __bf16* dst = P + (long)row * NC;
  bf16x4 h0, h1;
#pragma unroll
  for (int r = 0; r < 4; ++r) {
    h0[r] = (__bf16)(e[r] * inv);
    h1[r] = (__bf16)(e[4 + r] * inv);
  }
  *(bf16x4*)(dst + lane * 4) = h0;
  *(bf16x4*)(dst + 256 + lane * 4) = h1;
}

// ---------------------------------------------------------------------------
extern "C" void kernel_launch(void* const* d_in, const int* in_sizes, int n_in,
                              void* d_out, int out_size, void* d_ws,
                              size_t ws_size, hipStream_t stream) {
  const float* img = (const float*)d_in[0];   // q source
  const float* txt = (const float*)d_in[1];   // kv source
  const float* gamma = (const float*)d_in[2];
  float* out = (float*)d_out;

  char* ws = (char*)d_ws;
  // [0, 64MB): attn split-K partials (4 x 16.8MB f32); AFTER softmax this
  //            region is dead and kvT (64MB bf16) aliases it.
  // [64MB, 72MB): P (bf16)
  float* attnP = (float*)ws;
  __bf16* kvT = (__bf16*)ws;  // alias — written only after softmax completes
  __bf16* P = (__bf16*)(ws + (size_t)64 * 1024 * 1024);

  // 1) attn partials = q * kv^T  (per batch 512x512, K=4096 split 4 ways)
  gemm_bt<1, 0, NC, NC, NHW, SPLITK>
      <<<dim3(NC / 128, NC / 128, NB * SPLITK), 512, 0, stream>>>(
          img, txt, attnP, nullptr, nullptr, nullptr);

  // 2) P = softmax_rows(sum of partials), bf16
  softmax_rows<<<dim3(NB * NC / 4), 256, 0, stream>>>(attnP, P);

  // 3) kvT[b][n][d] = bf16(kv[b][d][n])   (aliases the dead partials region)
  transpose_cast<<<dim3(NHW / 64, NC / 64, NB), 256, 0, stream>>>(txt, kvT);

  // 4) D[n][c] = sum_d kvT[n][d]*P[c][d] = info[c][n];
  //    out[b][c][n] = gamma*D + img  (per batch 4096x512, K=512)
  gemm_bt<0, 1, NHW, NC, NC, 1>
      <<<dim3(NHW / 128, NC / 128, NB), 512, 0, stream>>>(
          kvT, P, nullptr, img, gamma, out);
}